// Round 1
// baseline (589.758 us; speedup 1.0000x reference)
//
#include <hip/hip_runtime.h>
#include <hip/hip_bf16.h>
#include <cstddef>

// Problem constants (from reference setup_inputs)
#define BATCH   4096
#define PAD_IDX 1000000
#define NEG_INF_F (-1e9f)

__device__ __forceinline__ float wave_sum(float v) {
    v += __shfl_xor(v, 32);
    v += __shfl_xor(v, 16);
    v += __shfl_xor(v, 8);
    v += __shfl_xor(v, 4);
    v += __shfl_xor(v, 2);
    v += __shfl_xor(v, 1);
    return v;
}

// Online-softmax update: s = score, v = this lane's embedding element
#define ONLINE_UPD(s, v)                              \
    {                                                 \
        float nm = fmaxf(m, (s));                     \
        float sc = __expf(m - nm);                    \
        float e  = __expf((s) - nm);                  \
        d   = fmaf(d, sc, e);                         \
        acc = fmaf(acc, sc, e * (v));                 \
        m   = nm;                                     \
    }

// One wave per task. Tasks:
//   w in [0, 3B)  : attention pool (history h = w/B, batch b = w%B)
//   w in [3B,11B) : ad-embedding gather (b = t/8, feature f = t%8)
// x layout per row (704 floats): [pool_item(64) | pool_author(64) | pool_music(64) | ad_emb(512)]
__global__ void __launch_bounds__(256) build_x_kernel(
    const int* __restrict__ fidx,
    const int* __restrict__ hist_item,
    const int* __restrict__ hist_author,
    const int* __restrict__ hist_music,
    const float* __restrict__ emb,
    float* __restrict__ x)
{
    const int w    = (blockIdx.x * 256 + threadIdx.x) >> 6;
    const int lane = threadIdx.x & 63;
    const int B = BATCH;

    if (w < 3 * B) {
        const int h = w >> 12;            // w / 4096
        const int b = w & (B - 1);        // w % 4096
        int L, col, off;
        const int* hrow;
        if (h == 0)      { L = 350; col = 2; off = 0;   hrow = hist_item   + (size_t)b * 350; }
        else if (h == 1) { L = 250; col = 3; off = 64;  hrow = hist_author + (size_t)b * 250; }
        else             { L = 100; col = 6; off = 128; hrow = hist_music  + (size_t)b * 100; }

        const int ad_idx = fidx[b * 8 + col];
        const float ad_k = emb[(size_t)ad_idx * 64 + lane];

        float m = NEG_INF_F, d = 0.f, acc = 0.f;
        int l = 0;
        for (; l + 4 <= L; l += 4) {
            const int i0 = hrow[l + 0];
            const int i1 = hrow[l + 1];
            const int i2 = hrow[l + 2];
            const int i3 = hrow[l + 3];
            // 4 independent coalesced 256B gathers in flight
            const float v0 = emb[(size_t)i0 * 64 + lane];
            const float v1 = emb[(size_t)i1 * 64 + lane];
            const float v2 = emb[(size_t)i2 * 64 + lane];
            const float v3 = emb[(size_t)i3 * 64 + lane];
            float s0 = wave_sum(v0 * ad_k);
            float s1 = wave_sum(v1 * ad_k);
            float s2 = wave_sum(v2 * ad_k);
            float s3 = wave_sum(v3 * ad_k);
            if (i0 == PAD_IDX) s0 = NEG_INF_F;
            if (i1 == PAD_IDX) s1 = NEG_INF_F;
            if (i2 == PAD_IDX) s2 = NEG_INF_F;
            if (i3 == PAD_IDX) s3 = NEG_INF_F;
            ONLINE_UPD(s0, v0)
            ONLINE_UPD(s1, v1)
            ONLINE_UPD(s2, v2)
            ONLINE_UPD(s3, v3)
        }
        for (; l < L; ++l) {
            const int i0 = hrow[l];
            const float v0 = emb[(size_t)i0 * 64 + lane];
            float s0 = wave_sum(v0 * ad_k);
            if (i0 == PAD_IDX) s0 = NEG_INF_F;
            ONLINE_UPD(s0, v0)
        }
        x[(size_t)b * 704 + off + lane] = acc / d;
    } else {
        const int t = w - 3 * B;          // [0, 8B)
        const int b = t >> 3;
        const int f = t & 7;
        const int idx = fidx[b * 8 + f];
        x[(size_t)b * 704 + 192 + f * 64 + lane] = emb[(size_t)idx * 64 + lane];
    }
}

// fp32 tiled GEMM: C[M,N] = act(A[M,K] @ W[K,N] + bias[N])
// BM=BN=64, BK=16, 256 threads, 4x4 micro-tile per thread.
// Requires M%64==0, N%64==0, K%16==0 (holds: M=4096, N in {512,256,128}, K in {704,512,256}).
template <bool RELU>
__global__ void __launch_bounds__(256) gemm_bias(
    const float* __restrict__ A,
    const float* __restrict__ W,
    const float* __restrict__ bias,
    float* __restrict__ C,
    int M, int N, int K)
{
    __shared__ float As[16][68];   // [kk][m], padded: float4-aligned rows, 2-way banks max
    __shared__ float Ws[16][64];   // [kk][n]

    const int tid = threadIdx.x;
    const int bm = blockIdx.y * 64;
    const int bn = blockIdx.x * 64;

    const int arow = tid >> 2;             // 0..63
    const int akq  = (tid & 3) << 2;       // 0,4,8,12
    const int wkk  = tid >> 4;             // 0..15
    const int wn   = (tid & 15) << 2;      // 0..60

    const int ty = tid >> 4, tx = tid & 15;
    const int m0 = ty << 2, n0 = tx << 2;

    float accm[4][4] = {};

    for (int k0 = 0; k0 < K; k0 += 16) {
        const float4 a4 = *(const float4*)(A + (size_t)(bm + arow) * K + k0 + akq);
        As[akq + 0][arow] = a4.x;
        As[akq + 1][arow] = a4.y;
        As[akq + 2][arow] = a4.z;
        As[akq + 3][arow] = a4.w;
        *(float4*)&Ws[wkk][wn] = *(const float4*)(W + (size_t)(k0 + wkk) * N + bn + wn);
        __syncthreads();

#pragma unroll
        for (int kk = 0; kk < 16; ++kk) {
            const float4 av = *(const float4*)&As[kk][m0];
            const float4 bv = *(const float4*)&Ws[kk][n0];
            const float a[4] = {av.x, av.y, av.z, av.w};
            const float b[4] = {bv.x, bv.y, bv.z, bv.w};
#pragma unroll
            for (int i = 0; i < 4; ++i)
#pragma unroll
                for (int j = 0; j < 4; ++j)
                    accm[i][j] = fmaf(a[i], b[j], accm[i][j]);
        }
        __syncthreads();
    }

#pragma unroll
    for (int i = 0; i < 4; ++i) {
#pragma unroll
        for (int j = 0; j < 4; ++j) {
            float v = accm[i][j] + bias[bn + n0 + j];
            if (RELU) v = fmaxf(v, 0.f);
            C[(size_t)(bm + m0 + i) * N + bn + n0 + j] = v;
        }
    }
}

// logits[b] = h3[b,:] @ Wo + bo   (one wave per row, 128 elems = 2/lane)
__global__ void __launch_bounds__(256) out_layer(
    const float* __restrict__ h3,
    const float* __restrict__ Wo,
    const float* __restrict__ bo,
    float* __restrict__ out, int M)
{
    const int w    = (blockIdx.x * 256 + threadIdx.x) >> 6;
    const int lane = threadIdx.x & 63;
    if (w >= M) return;
    float v = h3[(size_t)w * 128 + lane] * Wo[lane]
            + h3[(size_t)w * 128 + 64 + lane] * Wo[64 + lane];
    v = wave_sum(v);
    if (lane == 0) out[w] = v + bo[0];
}

extern "C" void kernel_launch(void* const* d_in, const int* in_sizes, int n_in,
                              void* d_out, int out_size, void* d_ws, size_t ws_size,
                              hipStream_t stream) {
    const int*   fidx  = (const int*)d_in[0];
    const int*   hitem = (const int*)d_in[1];
    const int*   hauth = (const int*)d_in[2];
    const int*   hmus  = (const int*)d_in[3];
    const float* emb   = (const float*)d_in[4];
    const float* W1 = (const float*)d_in[5];
    const float* b1 = (const float*)d_in[6];
    const float* W2 = (const float*)d_in[7];
    const float* b2 = (const float*)d_in[8];
    const float* W3 = (const float*)d_in[9];
    const float* b3 = (const float*)d_in[10];
    const float* Wo = (const float*)d_in[11];
    const float* bo = (const float*)d_in[12];
    float* out = (float*)d_out;

    // workspace: x[4096,704] | h1[4096,512] | h2[4096,256] | h3[4096,128]  (~26 MB)
    float* x  = (float*)d_ws;
    float* h1 = x  + (size_t)BATCH * 704;
    float* h2 = h1 + (size_t)BATCH * 512;
    float* h3 = h2 + (size_t)BATCH * 256;

    // 11*4096 wave-tasks, 4 waves/block -> 11264 blocks
    build_x_kernel<<<11 * BATCH / 4, 256, 0, stream>>>(fidx, hitem, hauth, hmus, emb, x);

    gemm_bias<true><<<dim3(512 / 64, BATCH / 64), 256, 0, stream>>>(x,  W1, b1, h1, BATCH, 512, 704);
    gemm_bias<true><<<dim3(256 / 64, BATCH / 64), 256, 0, stream>>>(h1, W2, b2, h2, BATCH, 256, 512);
    gemm_bias<true><<<dim3(128 / 64, BATCH / 64), 256, 0, stream>>>(h2, W3, b3, h3, BATCH, 128, 256);

    out_layer<<<BATCH / 4, 256, 0, stream>>>(h3, Wo, bo, out, BATCH);
}

// Round 2
// 497.113 us; speedup vs baseline: 1.1864x; 1.1864x over previous
//
#include <hip/hip_runtime.h>
#include <hip/hip_bf16.h>
#include <cstddef>

#define BATCH   4096
#define PAD_IDX 1000000
#define NEG_INF_F (-1e9f)

// Online-softmax update, per-quarter state (m, d scalar; acc float4).
#define UPD(s, v)                                     \
    {                                                 \
        float nm = fmaxf(m, (s));                     \
        float sc = __expf(m - nm);                    \
        float e  = __expf((s) - nm);                  \
        d = fmaf(d, sc, e);                           \
        acc.x = fmaf(acc.x, sc, e * (v).x);           \
        acc.y = fmaf(acc.y, sc, e * (v).y);           \
        acc.z = fmaf(acc.z, sc, e * (v).z);           \
        acc.w = fmaf(acc.w, sc, e * (v).w);           \
        m = nm;                                       \
    }

// Flash-merge this quarter's state with partner at lane^P.
#define MERGE(P)                                                  \
    {                                                             \
        float mo  = __shfl_xor(m, P);                             \
        float d_o = __shfl_xor(d, P);                             \
        float ax = __shfl_xor(acc.x, P);                          \
        float ay = __shfl_xor(acc.y, P);                          \
        float az = __shfl_xor(acc.z, P);                          \
        float aw = __shfl_xor(acc.w, P);                          \
        float nm = fmaxf(m, mo);                                  \
        float sA = __expf(m - nm), sB = __expf(mo - nm);          \
        d = d * sA + d_o * sB;                                    \
        acc.x = acc.x * sA + ax * sB;                             \
        acc.y = acc.y * sA + ay * sB;                             \
        acc.z = acc.z * sA + az * sB;                             \
        acc.w = acc.w * sA + aw * sB;                             \
        m = nm;                                                   \
    }

// 16-lane reduction (stays within each quarter since masks < 16)
#define QRED(s)                       \
    s += __shfl_xor(s, 1);            \
    s += __shfl_xor(s, 2);            \
    s += __shfl_xor(s, 4);            \
    s += __shfl_xor(s, 8);

// One wave per task; wave is split into 4 quarters of 16 lanes.
// Quarter q handles history item (l+q); lane t in quarter holds k=4t..4t+3.
//   w in [0, 3B)  : attention pool (h = w/B, b = w%B)
//   w in [3B, 5B) : ad-embedding gather, 4 features per wave
// x row layout (704 floats): [pool_item(64) | pool_author(64) | pool_music(64) | ad(512)]
__global__ void __launch_bounds__(256) build_x_kernel(
    const int* __restrict__ fidx,
    const int* __restrict__ hist_item,
    const int* __restrict__ hist_author,
    const int* __restrict__ hist_music,
    const float* __restrict__ emb,
    float* __restrict__ x)
{
    const int w    = (blockIdx.x * 256 + threadIdx.x) >> 6;
    const int lane = threadIdx.x & 63;
    const int t16  = lane & 15;
    const int q    = lane >> 4;

    if (w < 3 * BATCH) {
        const int h = w >> 12;
        const int b = w & (BATCH - 1);
        int L, col, off;
        const int* hrow;
        if (h == 0)      { L = 350; col = 2; off = 0;   hrow = hist_item   + (size_t)b * 350; }
        else if (h == 1) { L = 250; col = 3; off = 64;  hrow = hist_author + (size_t)b * 250; }
        else             { L = 100; col = 6; off = 128; hrow = hist_music  + (size_t)b * 100; }

        const int ad_idx = fidx[b * 8 + col];
        const float4 ad4 = *(const float4*)(emb + (size_t)ad_idx * 64 + 4 * t16);

        float m = NEG_INF_F, d = 0.f;
        float4 acc = make_float4(0.f, 0.f, 0.f, 0.f);

        int l = 0;
        // main loop: 8 items per iteration (2 gathers of 4 rows in flight)
        for (; l + 8 <= L; l += 8) {
            const int i0 = hrow[l + q];
            const int i1 = hrow[l + 4 + q];
            const float4 v0 = *(const float4*)(emb + (size_t)i0 * 64 + 4 * t16);
            const float4 v1 = *(const float4*)(emb + (size_t)i1 * 64 + 4 * t16);
            float s0 = v0.x * ad4.x + v0.y * ad4.y + v0.z * ad4.z + v0.w * ad4.w;
            float s1 = v1.x * ad4.x + v1.y * ad4.y + v1.z * ad4.z + v1.w * ad4.w;
            QRED(s0)
            QRED(s1)
            if (i0 == PAD_IDX) s0 = NEG_INF_F;
            if (i1 == PAD_IDX) s1 = NEG_INF_F;
            UPD(s0, v0)
            UPD(s1, v1)
        }
        // tail: 4 items per iteration, out-of-range -> PAD (zero weight)
        for (; l < L; l += 4) {
            const int li = l + q;
            const int i0 = (li < L) ? hrow[li] : PAD_IDX;
            const float4 v0 = *(const float4*)(emb + (size_t)i0 * 64 + 4 * t16);
            float s0 = v0.x * ad4.x + v0.y * ad4.y + v0.z * ad4.z + v0.w * ad4.w;
            QRED(s0)
            if (i0 == PAD_IDX) s0 = NEG_INF_F;
            UPD(s0, v0)
        }

        MERGE(16)
        MERGE(32)

        if (lane < 16) {
            const float inv = 1.f / d;
            float4 r = make_float4(acc.x * inv, acc.y * inv, acc.z * inv, acc.w * inv);
            *(float4*)(x + (size_t)b * 704 + off + 4 * t16) = r;
        }
    } else {
        const int tt = w - 3 * BATCH;          // [0, 2B)
        const int b  = tt >> 1;
        const int f  = ((tt & 1) << 2) + q;    // 4 features per wave
        const int idx = fidx[b * 8 + f];
        const float4 v = *(const float4*)(emb + (size_t)idx * 64 + 4 * t16);
        *(float4*)(x + (size_t)b * 704 + 192 + (size_t)f * 64 + 4 * t16) = v;
    }
}

// fp32 tiled GEMM: C[M,N] = act(A[M,K] @ W[K,N] + bias[N])
// BM=BN=64, BK=16, 256 threads, 4x4 micro-tile, register-prefetch pipeline.
template <bool RELU>
__global__ void __launch_bounds__(256) gemm_bias(
    const float* __restrict__ A,
    const float* __restrict__ W,
    const float* __restrict__ bias,
    float* __restrict__ C,
    int M, int N, int K)
{
    __shared__ float As[16][68];   // [kk][m], +4 pad
    __shared__ float Ws[16][64];   // [kk][n]

    const int tid = threadIdx.x;
    const int bm = blockIdx.y * 64;
    const int bn = blockIdx.x * 64;

    const int arow = tid >> 2;             // 0..63
    const int akq  = (tid & 3) << 2;       // 0,4,8,12
    const int wkk  = tid >> 4;             // 0..15
    const int wn   = (tid & 15) << 2;      // 0..60

    const int ty = tid >> 4, tx = tid & 15;
    const int m0 = ty << 2, n0 = tx << 2;

    float accm[4][4] = {};

    float4 a_reg = *(const float4*)(A + (size_t)(bm + arow) * K + akq);
    float4 w_reg = *(const float4*)(W + (size_t)wkk * N + bn + wn);

    for (int k0 = 0; k0 < K; k0 += 16) {
        As[akq + 0][arow] = a_reg.x;
        As[akq + 1][arow] = a_reg.y;
        As[akq + 2][arow] = a_reg.z;
        As[akq + 3][arow] = a_reg.w;
        *(float4*)&Ws[wkk][wn] = w_reg;
        __syncthreads();

        if (k0 + 16 < K) {
            a_reg = *(const float4*)(A + (size_t)(bm + arow) * K + (k0 + 16) + akq);
            w_reg = *(const float4*)(W + (size_t)(k0 + 16 + wkk) * N + bn + wn);
        }

#pragma unroll
        for (int kk = 0; kk < 16; ++kk) {
            const float4 av = *(const float4*)&As[kk][m0];
            const float4 bv = *(const float4*)&Ws[kk][n0];
            const float a[4] = {av.x, av.y, av.z, av.w};
            const float b[4] = {bv.x, bv.y, bv.z, bv.w};
#pragma unroll
            for (int i = 0; i < 4; ++i)
#pragma unroll
                for (int j = 0; j < 4; ++j)
                    accm[i][j] = fmaf(a[i], b[j], accm[i][j]);
        }
        __syncthreads();
    }

#pragma unroll
    for (int i = 0; i < 4; ++i) {
#pragma unroll
        for (int j = 0; j < 4; ++j) {
            float v = accm[i][j] + bias[bn + n0 + j];
            if (RELU) v = fmaxf(v, 0.f);
            C[(size_t)(bm + m0 + i) * N + bn + n0 + j] = v;
        }
    }
}

// logits[b] = h3[b,:] @ Wo + bo   (one wave per row)
__global__ void __launch_bounds__(256) out_layer(
    const float* __restrict__ h3,
    const float* __restrict__ Wo,
    const float* __restrict__ bo,
    float* __restrict__ out, int M)
{
    const int w    = (blockIdx.x * 256 + threadIdx.x) >> 6;
    const int lane = threadIdx.x & 63;
    if (w >= M) return;
    float v = h3[(size_t)w * 128 + lane] * Wo[lane]
            + h3[(size_t)w * 128 + 64 + lane] * Wo[64 + lane];
    v += __shfl_xor(v, 32);
    v += __shfl_xor(v, 16);
    v += __shfl_xor(v, 8);
    v += __shfl_xor(v, 4);
    v += __shfl_xor(v, 2);
    v += __shfl_xor(v, 1);
    if (lane == 0) out[w] = v + bo[0];
}

extern "C" void kernel_launch(void* const* d_in, const int* in_sizes, int n_in,
                              void* d_out, int out_size, void* d_ws, size_t ws_size,
                              hipStream_t stream) {
    const int*   fidx  = (const int*)d_in[0];
    const int*   hitem = (const int*)d_in[1];
    const int*   hauth = (const int*)d_in[2];
    const int*   hmus  = (const int*)d_in[3];
    const float* emb   = (const float*)d_in[4];
    const float* W1 = (const float*)d_in[5];
    const float* b1 = (const float*)d_in[6];
    const float* W2 = (const float*)d_in[7];
    const float* b2 = (const float*)d_in[8];
    const float* W3 = (const float*)d_in[9];
    const float* b3 = (const float*)d_in[10];
    const float* Wo = (const float*)d_in[11];
    const float* bo = (const float*)d_in[12];
    float* out = (float*)d_out;

    float* x  = (float*)d_ws;
    float* h1 = x  + (size_t)BATCH * 704;
    float* h2 = h1 + (size_t)BATCH * 512;
    float* h3 = h2 + (size_t)BATCH * 256;

    // 3B pool-waves + 2B ad-waves = 5B waves, 4 waves/block
    build_x_kernel<<<5 * BATCH / 4, 256, 0, stream>>>(fidx, hitem, hauth, hmus, emb, x);

    gemm_bias<true><<<dim3(512 / 64, BATCH / 64), 256, 0, stream>>>(x,  W1, b1, h1, BATCH, 512, 704);
    gemm_bias<true><<<dim3(256 / 64, BATCH / 64), 256, 0, stream>>>(h1, W2, b2, h2, BATCH, 256, 512);
    gemm_bias<true><<<dim3(128 / 64, BATCH / 64), 256, 0, stream>>>(h2, W3, b3, h3, BATCH, 128, 256);

    out_layer<<<BATCH / 4, 256, 0, stream>>>(h3, Wo, bo, out, BATCH);
}

// Round 3
// 450.384 us; speedup vs baseline: 1.3095x; 1.1038x over previous
//
#include <hip/hip_runtime.h>
#include <cstddef>

#define BATCH   4096
#define PAD_IDX 1000000
#define NEG_INF_F (-1e9f)

typedef __attribute__((ext_vector_type(8))) short bf16x8;   // 8 bf16 = 4 VGPRs
typedef __attribute__((ext_vector_type(4))) float f32x4;
typedef unsigned short u16;

__device__ __forceinline__ u16 f2bf(float f) {              // RNE fp32 -> bf16
    unsigned u = __float_as_uint(f);
    return (u16)((u + 0x7fffu + ((u >> 16) & 1u)) >> 16);
}
__device__ __forceinline__ float bf2f(u16 b) {
    return __uint_as_float(((unsigned)b) << 16);
}

// ---------------- build_x: 3 attention pools + ad gather, bf16 output ----------------

#define UPD(s, v)                                     \
    {                                                 \
        float nm = fmaxf(m, (s));                     \
        float sc = __expf(m - nm);                    \
        float e  = __expf((s) - nm);                  \
        d = fmaf(d, sc, e);                           \
        acc.x = fmaf(acc.x, sc, e * (v).x);           \
        acc.y = fmaf(acc.y, sc, e * (v).y);           \
        acc.z = fmaf(acc.z, sc, e * (v).z);           \
        acc.w = fmaf(acc.w, sc, e * (v).w);           \
        m = nm;                                       \
    }

#define MERGE(P)                                                  \
    {                                                             \
        float mo  = __shfl_xor(m, P);                             \
        float d_o = __shfl_xor(d, P);                             \
        float ax = __shfl_xor(acc.x, P);                          \
        float ay = __shfl_xor(acc.y, P);                          \
        float az = __shfl_xor(acc.z, P);                          \
        float aw = __shfl_xor(acc.w, P);                          \
        float nm = fmaxf(m, mo);                                  \
        float sA = __expf(m - nm), sB = __expf(mo - nm);          \
        d = d * sA + d_o * sB;                                    \
        acc.x = acc.x * sA + ax * sB;                             \
        acc.y = acc.y * sA + ay * sB;                             \
        acc.z = acc.z * sA + az * sB;                             \
        acc.w = acc.w * sA + aw * sB;                             \
        m = nm;                                                   \
    }

#define QRED(s)                       \
    s += __shfl_xor(s, 1);            \
    s += __shfl_xor(s, 2);            \
    s += __shfl_xor(s, 4);            \
    s += __shfl_xor(s, 8);

// x row layout (704 bf16): [pool_item(64) | pool_author(64) | pool_music(64) | ad(512)]
__global__ void __launch_bounds__(256) build_x_kernel(
    const int* __restrict__ fidx,
    const int* __restrict__ hist_item,
    const int* __restrict__ hist_author,
    const int* __restrict__ hist_music,
    const float* __restrict__ emb,
    u16* __restrict__ x)
{
    const int w    = (blockIdx.x * 256 + threadIdx.x) >> 6;
    const int lane = threadIdx.x & 63;
    const int t16  = lane & 15;
    const int q    = lane >> 4;

    if (w < 3 * BATCH) {
        const int h = w >> 12;
        const int b = w & (BATCH - 1);
        int L, col, off;
        const int* hrow;
        if (h == 0)      { L = 350; col = 2; off = 0;   hrow = hist_item   + (size_t)b * 350; }
        else if (h == 1) { L = 250; col = 3; off = 64;  hrow = hist_author + (size_t)b * 250; }
        else             { L = 100; col = 6; off = 128; hrow = hist_music  + (size_t)b * 100; }

        const int ad_idx = fidx[b * 8 + col];
        const float4 ad4 = *(const float4*)(emb + (size_t)ad_idx * 64 + 4 * t16);

        float m = NEG_INF_F, d = 0.f;
        float4 acc = make_float4(0.f, 0.f, 0.f, 0.f);

        int l = 0;
        for (; l + 8 <= L; l += 8) {
            const int i0 = hrow[l + q];
            const int i1 = hrow[l + 4 + q];
            const float4 v0 = *(const float4*)(emb + (size_t)i0 * 64 + 4 * t16);
            const float4 v1 = *(const float4*)(emb + (size_t)i1 * 64 + 4 * t16);
            float s0 = v0.x * ad4.x + v0.y * ad4.y + v0.z * ad4.z + v0.w * ad4.w;
            float s1 = v1.x * ad4.x + v1.y * ad4.y + v1.z * ad4.z + v1.w * ad4.w;
            QRED(s0)
            QRED(s1)
            if (i0 == PAD_IDX) s0 = NEG_INF_F;
            if (i1 == PAD_IDX) s1 = NEG_INF_F;
            UPD(s0, v0)
            UPD(s1, v1)
        }
        for (; l < L; l += 4) {
            const int li = l + q;
            const int i0 = (li < L) ? hrow[li] : PAD_IDX;
            const float4 v0 = *(const float4*)(emb + (size_t)i0 * 64 + 4 * t16);
            float s0 = v0.x * ad4.x + v0.y * ad4.y + v0.z * ad4.z + v0.w * ad4.w;
            QRED(s0)
            if (i0 == PAD_IDX) s0 = NEG_INF_F;
            UPD(s0, v0)
        }

        MERGE(16)
        MERGE(32)

        if (lane < 16) {
            const float inv = 1.f / d;
            uint2 p;
            p.x = (unsigned)f2bf(acc.x * inv) | ((unsigned)f2bf(acc.y * inv) << 16);
            p.y = (unsigned)f2bf(acc.z * inv) | ((unsigned)f2bf(acc.w * inv) << 16);
            *(uint2*)(x + (size_t)b * 704 + off + 4 * t16) = p;
        }
    } else {
        const int tt = w - 3 * BATCH;          // [0, 2B)
        const int b  = tt >> 1;
        const int f  = ((tt & 1) << 2) + q;    // 4 features per wave
        const int idx = fidx[b * 8 + f];
        const float4 v = *(const float4*)(emb + (size_t)idx * 64 + 4 * t16);
        uint2 p;
        p.x = (unsigned)f2bf(v.x) | ((unsigned)f2bf(v.y) << 16);
        p.y = (unsigned)f2bf(v.z) | ((unsigned)f2bf(v.w) << 16);
        *(uint2*)(x + (size_t)b * 704 + 192 + (size_t)f * 64 + 4 * t16) = p;
    }
}

// ---------------- weight conversion: fp32 [K][N] -> bf16 transposed [N][K] ----------------
__global__ void __launch_bounds__(256) convert_weights(
    const float* __restrict__ W1, const float* __restrict__ W2, const float* __restrict__ W3,
    u16* __restrict__ W1T, u16* __restrict__ W2T, u16* __restrict__ W3T)
{
    int i = blockIdx.x * 256 + threadIdx.x;
    if (i < 704 * 512) {                       // W1: K=704, N=512
        const int n = i / 704, k = i - n * 704;
        W1T[i] = f2bf(W1[(size_t)k * 512 + n]);
        return;
    }
    i -= 704 * 512;
    if (i < 512 * 256) {                       // W2: K=512, N=256
        const int n = i / 512, k = i - n * 512;
        W2T[i] = f2bf(W2[(size_t)k * 256 + n]);
        return;
    }
    i -= 512 * 256;
    if (i < 256 * 128) {                       // W3: K=256, N=128
        const int n = i / 256, k = i - n * 256;
        W3T[i] = f2bf(W3[(size_t)k * 128 + n]);
    }
}

// ---------------- bf16 MFMA GEMM: C[M,N] = act(A[M,K] @ BT[N,K]^T + bias) ----------------
// BM=64, 256 threads = 4 waves (wave w owns rows w*16..+16), BK=32.
// LDS rows padded to 40 bf16 (80 B) -> b128 frag reads are <=2-way bank-aliased (free).
// Fragment layouts (m89/m120-verified): A[m=lane&15][k=quad*8+j]; B[k=quad*8+j][n=lane&15];
// C/D: row=quad*4+reg, col=lane&15.
template <int BN, bool RELU>
__global__ void __launch_bounds__(256) gemm_mfma(
    const u16* __restrict__ A, const u16* __restrict__ BT,
    const float* __restrict__ bias, u16* __restrict__ C,
    int M, int N, int K)
{
    constexpr int NB = BN / 16;
    __shared__ u16 As[64][40];
    __shared__ u16 Bs[BN][40];

    const int tid  = threadIdx.x;
    const int wave = tid >> 6, lane = tid & 63;
    const int quad = lane >> 4, l16 = lane & 15;
    const int bm = blockIdx.y * 64, bn = blockIdx.x * BN;

    const int srow = tid >> 2;          // 0..63
    const int sk   = (tid & 3) * 8;     // 0,8,16,24 (bf16 elems)

    f32x4 acc[NB];
#pragma unroll
    for (int i = 0; i < NB; ++i) acc[i] = (f32x4){0.f, 0.f, 0.f, 0.f};

    const size_t a_base = (size_t)(bm + srow) * K + sk;

    for (int k0 = 0; k0 < K; k0 += 32) {
        *(float4*)&As[srow][sk] = *(const float4*)(A + a_base + k0);
#pragma unroll
        for (int r0 = 0; r0 < BN; r0 += 64) {
            *(float4*)&Bs[r0 + srow][sk] =
                *(const float4*)(BT + (size_t)(bn + r0 + srow) * K + k0 + sk);
        }
        __syncthreads();

        const bf16x8 af = *(const bf16x8*)&As[wave * 16 + l16][quad * 8];
#pragma unroll
        for (int ni = 0; ni < NB; ++ni) {
            const bf16x8 bf = *(const bf16x8*)&Bs[ni * 16 + l16][quad * 8];
            acc[ni] = __builtin_amdgcn_mfma_f32_16x16x32_bf16(af, bf, acc[ni], 0, 0, 0);
        }
        __syncthreads();
    }

#pragma unroll
    for (int ni = 0; ni < NB; ++ni) {
        const int col = bn + ni * 16 + l16;
        const float bv = bias[col];
#pragma unroll
        for (int r = 0; r < 4; ++r) {
            const int row = bm + wave * 16 + quad * 4 + r;
            float v = acc[ni][r] + bv;
            if (RELU) v = fmaxf(v, 0.f);
            C[(size_t)row * N + col] = f2bf(v);
        }
    }
}

// ---------------- final 128->1 dot (fp32) ----------------
__global__ void __launch_bounds__(256) out_layer(
    const u16* __restrict__ h3,
    const float* __restrict__ Wo,
    const float* __restrict__ bo,
    float* __restrict__ out, int M)
{
    const int w    = (blockIdx.x * 256 + threadIdx.x) >> 6;
    const int lane = threadIdx.x & 63;
    if (w >= M) return;
    float v = bf2f(h3[(size_t)w * 128 + lane]) * Wo[lane]
            + bf2f(h3[(size_t)w * 128 + 64 + lane]) * Wo[64 + lane];
    v += __shfl_xor(v, 32);
    v += __shfl_xor(v, 16);
    v += __shfl_xor(v, 8);
    v += __shfl_xor(v, 4);
    v += __shfl_xor(v, 2);
    v += __shfl_xor(v, 1);
    if (lane == 0) out[w] = v + bo[0];
}

extern "C" void kernel_launch(void* const* d_in, const int* in_sizes, int n_in,
                              void* d_out, int out_size, void* d_ws, size_t ws_size,
                              hipStream_t stream) {
    const int*   fidx  = (const int*)d_in[0];
    const int*   hitem = (const int*)d_in[1];
    const int*   hauth = (const int*)d_in[2];
    const int*   hmus  = (const int*)d_in[3];
    const float* emb   = (const float*)d_in[4];
    const float* W1 = (const float*)d_in[5];
    const float* b1 = (const float*)d_in[6];
    const float* W2 = (const float*)d_in[7];
    const float* b2 = (const float*)d_in[8];
    const float* W3 = (const float*)d_in[9];
    const float* b3 = (const float*)d_in[10];
    const float* Wo = (const float*)d_in[11];
    const float* bo = (const float*)d_in[12];
    float* out = (float*)d_out;

    // workspace carve (all 16B-aligned, bf16 elements)
    u16* x   = (u16*)d_ws;                     // 4096*704
    u16* h1  = x   + (size_t)BATCH * 704;      // 4096*512
    u16* h2  = h1  + (size_t)BATCH * 512;      // 4096*256
    u16* h3  = h2  + (size_t)BATCH * 256;      // 4096*128
    u16* w1t = h3  + (size_t)BATCH * 128;      // 512*704
    u16* w2t = w1t + (size_t)704 * 512;        // 256*512
    u16* w3t = w2t + (size_t)512 * 256;        // 128*256

    convert_weights<<<(704 * 512 + 512 * 256 + 256 * 128) / 256, 256, 0, stream>>>(
        W1, W2, W3, w1t, w2t, w3t);

    build_x_kernel<<<5 * BATCH / 4, 256, 0, stream>>>(fidx, hitem, hauth, hmus, emb, x);

    gemm_mfma<128, true><<<dim3(512 / 128, BATCH / 64), 256, 0, stream>>>(
        x, w1t, b1, h1, BATCH, 512, 704);
    gemm_mfma<64, true><<<dim3(256 / 64, BATCH / 64), 256, 0, stream>>>(
        h1, w2t, b2, h2, BATCH, 256, 512);
    gemm_mfma<64, true><<<dim3(128 / 64, BATCH / 64), 256, 0, stream>>>(
        h2, w3t, b3, h3, BATCH, 128, 256);

    out_layer<<<BATCH / 4, 256, 0, stream>>>(h3, Wo, bo, out, BATCH);
}

// Round 4
// 445.299 us; speedup vs baseline: 1.3244x; 1.0114x over previous
//
#include <hip/hip_runtime.h>
#include <cstddef>

#define BATCH   4096
#define PAD_IDX 1000000
#define NEG_INF_F (-1e9f)

typedef __attribute__((ext_vector_type(8))) short bf16x8;   // 8 bf16 = 4 VGPRs
typedef __attribute__((ext_vector_type(4))) float f32x4;
typedef unsigned short u16;

__device__ __forceinline__ u16 f2bf(float f) {              // RNE fp32 -> bf16
    unsigned u = __float_as_uint(f);
    return (u16)((u + 0x7fffu + ((u >> 16) & 1u)) >> 16);
}
__device__ __forceinline__ float bf2f(u16 b) {
    return __uint_as_float(((unsigned)b) << 16);
}

// Online-softmax update on named state (mm, dd, aa)
#define UPD(mm, dd, aa, s, v)                          \
    {                                                  \
        float nm = fmaxf(mm, (s));                     \
        float sc = __expf(mm - nm);                    \
        float e  = __expf((s) - nm);                   \
        dd = fmaf(dd, sc, e);                          \
        aa.x = fmaf(aa.x, sc, e * (v).x);              \
        aa.y = fmaf(aa.y, sc, e * (v).y);              \
        aa.z = fmaf(aa.z, sc, e * (v).z);              \
        aa.w = fmaf(aa.w, sc, e * (v).w);              \
        mm = nm;                                       \
    }

// Flash-merge state A with partner at lane^P (acts on m,d,acc)
#define MERGE(P)                                                  \
    {                                                             \
        float mo  = __shfl_xor(m, P);                             \
        float d_o = __shfl_xor(d, P);                             \
        float ax = __shfl_xor(acc.x, P);                          \
        float ay = __shfl_xor(acc.y, P);                          \
        float az = __shfl_xor(acc.z, P);                          \
        float aw = __shfl_xor(acc.w, P);                          \
        float nm = fmaxf(m, mo);                                  \
        float sA = __expf(m - nm), sB = __expf(mo - nm);          \
        d = d * sA + d_o * sB;                                    \
        acc.x = acc.x * sA + ax * sB;                             \
        acc.y = acc.y * sA + ay * sB;                             \
        acc.z = acc.z * sA + az * sB;                             \
        acc.w = acc.w * sA + aw * sB;                             \
        m = nm;                                                   \
    }

#define QRED(s)                       \
    s += __shfl_xor(s, 1);            \
    s += __shfl_xor(s, 2);            \
    s += __shfl_xor(s, 4);            \
    s += __shfl_xor(s, 8);

#define DOT4(v, a) ((v).x * (a).x + (v).y * (a).y + (v).z * (a).z + (v).w * (a).w)

// ---------------- prep: attention pools + ad gather (bf16 x) fused with weight transpose ----------------
// Blocks [0, 5120): build_x — wave w = blk*4+waveid; wave split into 4 quarters of 16 lanes,
//   quarter q handles item l+q (float4/lane over K=64).
//   w in [0, 3B): pools; w in [3B, 5B): ad gather (4 features/wave).
// Blocks [5120, 5632): 32x32 LDS-tiled transpose W[K][N] fp32 -> WT[N][K] bf16.
// x row layout (704 bf16): [pool_item(64) | pool_author(64) | pool_music(64) | ad(512)]
__global__ void __launch_bounds__(256) prep_kernel(
    const int* __restrict__ fidx,
    const int* __restrict__ hist_item,
    const int* __restrict__ hist_author,
    const int* __restrict__ hist_music,
    const float* __restrict__ emb,
    const float* __restrict__ W1, const float* __restrict__ W2, const float* __restrict__ W3,
    u16* __restrict__ x,
    u16* __restrict__ w1t, u16* __restrict__ w2t, u16* __restrict__ w3t)
{
    __shared__ float tile[32][33];
    const int blk = blockIdx.x;

    if (blk < 5120) {
        const int w    = blk * 4 + (threadIdx.x >> 6);
        const int lane = threadIdx.x & 63;
        const int t16  = lane & 15;
        const int q    = lane >> 4;

        if (w < 3 * BATCH) {
            const int h = w >> 12;
            const int b = w & (BATCH - 1);
            int L, col, off;
            const int* hrow;
            if (h == 0)      { L = 350; col = 2; off = 0;   hrow = hist_item   + (size_t)b * 350; }
            else if (h == 1) { L = 250; col = 3; off = 64;  hrow = hist_author + (size_t)b * 250; }
            else             { L = 100; col = 6; off = 128; hrow = hist_music  + (size_t)b * 100; }

            const int ad_idx = fidx[b * 8 + col];
            const float4 ad4 = *(const float4*)(emb + (size_t)ad_idx * 64 + 4 * t16);

            // dual softmax states to halve the serial UPD chain
            float m = NEG_INF_F, d = 0.f;
            float4 acc = make_float4(0.f, 0.f, 0.f, 0.f);
            float mB = NEG_INF_F, dB = 0.f;
            float4 aB = make_float4(0.f, 0.f, 0.f, 0.f);

            int l = 0;
            if (L >= 16) {
                int n0 = hrow[q], n1 = hrow[4 + q], n2 = hrow[8 + q], n3 = hrow[12 + q];
                while (true) {
                    const int i0 = n0, i1 = n1, i2 = n2, i3 = n3;
                    const float4 v0 = *(const float4*)(emb + (size_t)i0 * 64 + 4 * t16);
                    const float4 v1 = *(const float4*)(emb + (size_t)i1 * 64 + 4 * t16);
                    const float4 v2 = *(const float4*)(emb + (size_t)i2 * 64 + 4 * t16);
                    const float4 v3 = *(const float4*)(emb + (size_t)i3 * 64 + 4 * t16);
                    l += 16;
                    const bool more = (l + 16 <= L);
                    if (more) {  // prefetch next indices while gathers are in flight
                        n0 = hrow[l + q];      n1 = hrow[l + 4 + q];
                        n2 = hrow[l + 8 + q];  n3 = hrow[l + 12 + q];
                    }
                    float s0 = DOT4(v0, ad4);
                    float s1 = DOT4(v1, ad4);
                    float s2 = DOT4(v2, ad4);
                    float s3 = DOT4(v3, ad4);
                    QRED(s0) QRED(s1) QRED(s2) QRED(s3)
                    if (i0 == PAD_IDX) s0 = NEG_INF_F;
                    if (i1 == PAD_IDX) s1 = NEG_INF_F;
                    if (i2 == PAD_IDX) s2 = NEG_INF_F;
                    if (i3 == PAD_IDX) s3 = NEG_INF_F;
                    UPD(m, d, acc, s0, v0)
                    UPD(mB, dB, aB, s1, v1)
                    UPD(m, d, acc, s2, v2)
                    UPD(mB, dB, aB, s3, v3)
                    if (!more) break;
                }
            }
            for (; l < L; l += 4) {           // tail, 4 items/iter, OOB -> PAD (weight 0)
                const int li = l + q;
                const int i0 = (li < L) ? hrow[li] : PAD_IDX;
                const float4 v0 = *(const float4*)(emb + (size_t)i0 * 64 + 4 * t16);
                float s0 = DOT4(v0, ad4);
                QRED(s0)
                if (i0 == PAD_IDX) s0 = NEG_INF_F;
                UPD(m, d, acc, s0, v0)
            }

            // merge state B into A (local, no shuffles)
            {
                float nm = fmaxf(m, mB);
                float eA = __expf(m - nm), eB = __expf(mB - nm);
                d = d * eA + dB * eB;
                acc.x = acc.x * eA + aB.x * eB;
                acc.y = acc.y * eA + aB.y * eB;
                acc.z = acc.z * eA + aB.z * eB;
                acc.w = acc.w * eA + aB.w * eB;
                m = nm;
            }
            MERGE(16)
            MERGE(32)

            if (lane < 16) {
                const float inv = 1.f / d;
                uint2 p;
                p.x = (unsigned)f2bf(acc.x * inv) | ((unsigned)f2bf(acc.y * inv) << 16);
                p.y = (unsigned)f2bf(acc.z * inv) | ((unsigned)f2bf(acc.w * inv) << 16);
                *(uint2*)(x + (size_t)b * 704 + off + 4 * t16) = p;
            }
        } else {
            const int tt = w - 3 * BATCH;          // [0, 2B)
            const int b  = tt >> 1;
            const int f  = ((tt & 1) << 2) + q;    // 4 features per wave
            const int idx = fidx[b * 8 + f];
            const float4 v = *(const float4*)(emb + (size_t)idx * 64 + 4 * t16);
            uint2 p;
            p.x = (unsigned)f2bf(v.x) | ((unsigned)f2bf(v.y) << 16);
            p.y = (unsigned)f2bf(v.z) | ((unsigned)f2bf(v.w) << 16);
            *(uint2*)(x + (size_t)b * 704 + 192 + (size_t)f * 64 + 4 * t16) = p;
        }
    } else {
        // ---- weight transpose: 32x32 fp32 tile, coalesced read + coalesced write ----
        int t = blk - 5120;
        const float* W; u16* WT; int K, N, tk, tn;
        if (t < 352)      { W = W1; WT = w1t; K = 704; N = 512; tk = t % 22; tn = t / 22; }
        else if (t < 480) { t -= 352; W = W2; WT = w2t; K = 512; N = 256; tk = t % 16; tn = t / 16; }
        else              { t -= 480; W = W3; WT = w3t; K = 256; N = 128; tk = t % 8;  tn = t / 8;  }
        const int k0 = tk * 32, n0 = tn * 32;
        const int tx = threadIdx.x & 31, ty = threadIdx.x >> 5;   // ty 0..7
#pragma unroll
        for (int j = 0; j < 4; ++j)
            tile[ty + 8 * j][tx] = W[(size_t)(k0 + ty + 8 * j) * N + n0 + tx];
        __syncthreads();
#pragma unroll
        for (int j = 0; j < 4; ++j)
            WT[(size_t)(n0 + ty + 8 * j) * K + k0 + tx] = f2bf(tile[tx][ty + 8 * j]);
    }
}

// ---------------- bf16 MFMA GEMM: C[M,N] = relu(A[M,K] @ BT[N,K]^T + bias), bf16 out ----------------
// BM=64, 256 threads = 4 waves, BK=32. LDS rows padded to 40 bf16 (80 B).
// Fragments: A[m=lane&15][k=quad*8+j]; B[k=quad*8+j][n=lane&15]; C/D row=quad*4+reg, col=lane&15.
template <int BN>
__global__ void __launch_bounds__(256) gemm_mfma(
    const u16* __restrict__ A, const u16* __restrict__ BT,
    const float* __restrict__ bias, u16* __restrict__ C,
    int M, int N, int K)
{
    constexpr int NB = BN / 16;
    __shared__ u16 As[64][40];
    __shared__ u16 Bs[BN][40];

    const int tid  = threadIdx.x;
    const int wave = tid >> 6, lane = tid & 63;
    const int quad = lane >> 4, l16 = lane & 15;
    const int bm = blockIdx.y * 64, bn = blockIdx.x * BN;

    const int srow = tid >> 2;          // 0..63
    const int sk   = (tid & 3) * 8;     // 0,8,16,24

    f32x4 acc[NB];
#pragma unroll
    for (int i = 0; i < NB; ++i) acc[i] = (f32x4){0.f, 0.f, 0.f, 0.f};

    const size_t a_base = (size_t)(bm + srow) * K + sk;

    for (int k0 = 0; k0 < K; k0 += 32) {
        *(float4*)&As[srow][sk] = *(const float4*)(A + a_base + k0);
#pragma unroll
        for (int r0 = 0; r0 < BN; r0 += 64) {
            *(float4*)&Bs[r0 + srow][sk] =
                *(const float4*)(BT + (size_t)(bn + r0 + srow) * K + k0 + sk);
        }
        __syncthreads();

        const bf16x8 af = *(const bf16x8*)&As[wave * 16 + l16][quad * 8];
#pragma unroll
        for (int ni = 0; ni < NB; ++ni) {
            const bf16x8 bf = *(const bf16x8*)&Bs[ni * 16 + l16][quad * 8];
            acc[ni] = __builtin_amdgcn_mfma_f32_16x16x32_bf16(af, bf, acc[ni], 0, 0, 0);
        }
        __syncthreads();
    }

#pragma unroll
    for (int ni = 0; ni < NB; ++ni) {
        const int col = bn + ni * 16 + l16;
        const float bv = bias[col];
#pragma unroll
        for (int r = 0; r < 4; ++r) {
            const int row = bm + wave * 16 + quad * 4 + r;
            float v = fmaxf(acc[ni][r] + bv, 0.f);
            C[(size_t)row * N + col] = f2bf(v);
        }
    }
}

// ---------------- fused layer 3 + output: out = relu(h2 @ W3T^T + b3) @ Wo + bo ----------------
// M=4096, N=128, K=256. One block covers 64 rows x all 128 cols; grid = 64 blocks.
__global__ void __launch_bounds__(256) gemm3_out(
    const u16* __restrict__ A, const u16* __restrict__ BT,
    const float* __restrict__ bias,
    const float* __restrict__ Wo, const float* __restrict__ bo,
    float* __restrict__ out)
{
    constexpr int K = 256, NB = 8;
    __shared__ u16 As[64][40];
    __shared__ u16 Bs[128][40];

    const int tid  = threadIdx.x;
    const int wave = tid >> 6, lane = tid & 63;
    const int quad = lane >> 4, l16 = lane & 15;
    const int bm = blockIdx.x * 64;

    const int srow = tid >> 2;
    const int sk   = (tid & 3) * 8;

    f32x4 acc[NB];
#pragma unroll
    for (int i = 0; i < NB; ++i) acc[i] = (f32x4){0.f, 0.f, 0.f, 0.f};

    const size_t a_base = (size_t)(bm + srow) * K + sk;

    for (int k0 = 0; k0 < K; k0 += 32) {
        *(float4*)&As[srow][sk] = *(const float4*)(A + a_base + k0);
#pragma unroll
        for (int r0 = 0; r0 < 128; r0 += 64) {
            *(float4*)&Bs[r0 + srow][sk] =
                *(const float4*)(BT + (size_t)(r0 + srow) * K + k0 + sk);
        }
        __syncthreads();

        const bf16x8 af = *(const bf16x8*)&As[wave * 16 + l16][quad * 8];
#pragma unroll
        for (int ni = 0; ni < NB; ++ni) {
            const bf16x8 bf = *(const bf16x8*)&Bs[ni * 16 + l16][quad * 8];
            acc[ni] = __builtin_amdgcn_mfma_f32_16x16x32_bf16(af, bf, acc[ni], 0, 0, 0);
        }
        __syncthreads();
    }

    // epilogue: relu(+bias), dot with Wo across the 128 cols, reduce over 16 lanes
    float part[4] = {0.f, 0.f, 0.f, 0.f};
#pragma unroll
    for (int ni = 0; ni < NB; ++ni) {
        const int col = ni * 16 + l16;
        const float bv = bias[col];
        const float wv = Wo[col];
#pragma unroll
        for (int r = 0; r < 4; ++r)
            part[r] = fmaf(fmaxf(acc[ni][r] + bv, 0.f), wv, part[r]);
    }
#pragma unroll
    for (int r = 0; r < 4; ++r) {
        part[r] += __shfl_xor(part[r], 1);
        part[r] += __shfl_xor(part[r], 2);
        part[r] += __shfl_xor(part[r], 4);
        part[r] += __shfl_xor(part[r], 8);
    }
    if (l16 == 0) {
        const float b0 = bo[0];
#pragma unroll
        for (int r = 0; r < 4; ++r)
            out[bm + wave * 16 + quad * 4 + r] = part[r] + b0;
    }
}

extern "C" void kernel_launch(void* const* d_in, const int* in_sizes, int n_in,
                              void* d_out, int out_size, void* d_ws, size_t ws_size,
                              hipStream_t stream) {
    const int*   fidx  = (const int*)d_in[0];
    const int*   hitem = (const int*)d_in[1];
    const int*   hauth = (const int*)d_in[2];
    const int*   hmus  = (const int*)d_in[3];
    const float* emb   = (const float*)d_in[4];
    const float* W1 = (const float*)d_in[5];
    const float* b1 = (const float*)d_in[6];
    const float* W2 = (const float*)d_in[7];
    const float* b2 = (const float*)d_in[8];
    const float* W3 = (const float*)d_in[9];
    const float* b3 = (const float*)d_in[10];
    const float* Wo = (const float*)d_in[11];
    const float* bo = (const float*)d_in[12];
    float* out = (float*)d_out;

    // workspace carve (bf16 elements, all 16B-aligned)
    u16* x   = (u16*)d_ws;                     // 4096*704
    u16* h1  = x   + (size_t)BATCH * 704;      // 4096*512
    u16* h2  = h1  + (size_t)BATCH * 512;      // 4096*256
    u16* w1t = h2  + (size_t)BATCH * 256;      // 512*704
    u16* w2t = w1t + (size_t)704 * 512;        // 256*512
    u16* w3t = w2t + (size_t)512 * 256;        // 128*256

    // 5120 build_x blocks + 512 transpose blocks
    prep_kernel<<<5632, 256, 0, stream>>>(fidx, hitem, hauth, hmus, emb,
                                          W1, W2, W3, x, w1t, w2t, w3t);

    gemm_mfma<64><<<dim3(512 / 64, BATCH / 64), 256, 0, stream>>>(
        x, w1t, b1, h1, BATCH, 512, 704);
    gemm_mfma<64><<<dim3(256 / 64, BATCH / 64), 256, 0, stream>>>(
        h1, w2t, b2, h2, BATCH, 256, 512);
    gemm3_out<<<BATCH / 64, 256, 0, stream>>>(h2, w3t, b3, Wo, bo, out);
}